// Round 1
// baseline (295.635 us; speedup 1.0000x reference)
//
#include <hip/hip_runtime.h>
#include <cstdint>

#define F_IN  8
#define HID   64
#define F_OUTD 8
#define RDIM  256
#define CDIM  4096
#define NSETS 3
#define NIND  4096
#define MDIM  4096

// ---------------- zero fill (graph-capture-safe memset) ----------------
__global__ void zero_kernel(float4* __restrict__ p, int n4) {
    int i = blockIdx.x * blockDim.x + threadIdx.x;
    if (i < n4) p[i] = make_float4(0.f, 0.f, 0.f, 0.f);
}

// ---------------- batched tiled transpose: src [F][M][N] -> dst [F][N][M] ----
__global__ void transpose_f(const float* __restrict__ src, float* __restrict__ dst,
                            int M, int N) {
    __shared__ float tile[32][33];
    int f = blockIdx.z;
    const float* s = src + (size_t)f * M * N;
    float*       d = dst + (size_t)f * M * N;
    int n0 = blockIdx.x * 32, m0 = blockIdx.y * 32;
    int tx = threadIdx.x, ty = threadIdx.y;   // block (32, 8)
#pragma unroll
    for (int i = 0; i < 32; i += 8)
        tile[ty + i][tx] = s[(size_t)(m0 + ty + i) * N + n0 + tx];
    __syncthreads();
#pragma unroll
    for (int i = 0; i < 32; i += 8)
        d[(size_t)(n0 + ty + i) * M + m0 + tx] = tile[tx][ty + i];
}

// ---------------- build inverse permutations of col0 ----------------
// inv[si][c0] = k  such that ind_i[s][k][0] == c0       (si = s*3+i)
__global__ void build_inv(const int* __restrict__ ind0, const int* __restrict__ ind1,
                          const int* __restrict__ ind2, int* __restrict__ inv) {
    int k  = blockIdx.x * 256 + threadIdx.x;
    int si = blockIdx.y;
    int s_ = si / 3, i_ = si % 3;
    const int* ind = (i_ == 0 ? ind0 : (i_ == 1 ? ind1 : ind2)) + (size_t)s_ * NIND * 2;
    int c0 = ind[2 * k];
    inv[(size_t)si * NIND + c0] = k;
}

// ---------------- build gather/scatter column tables ----------------
// g[si][m] = col1[ inv[ mi ] ]  (source column, via inverse perm — project())
// h[si][m] = col1[ mi ]         (dest column, direct indexing — scatter idx)
__global__ void build_gh(const int* __restrict__ ind0, const int* __restrict__ ind1,
                         const int* __restrict__ ind2, const int* __restrict__ mix,
                         const int* __restrict__ inv,
                         int* __restrict__ g, int* __restrict__ h) {
    int m  = blockIdx.x * 256 + threadIdx.x;
    int si = blockIdx.y;
    int s_ = si / 3, i_ = si % 3;
    const int* ind = (i_ == 0 ? ind0 : (i_ == 1 ? ind1 : ind2)) + (size_t)s_ * NIND * 2;
    int mi = mix[(size_t)si * MDIM + m];
    h[(size_t)si * MDIM + m] = ind[2 * mi + 1];
    int k = inv[(size_t)si * NIND + mi];
    g[(size_t)si * MDIM + m] = ind[2 * k + 1];
}

// ---------------- fused gather -> MLP -> amax scatter ----------------
// One block per (s, m): 256 threads = r. inT is [f][c][r]; outT is [f][c][r] uint-punned.
__global__ __launch_bounds__(256)
void mlp_scatter(const float* __restrict__ inT,
                 const float* __restrict__ w1, const float* __restrict__ b1,
                 const float* __restrict__ w2, const float* __restrict__ b2,
                 const int* __restrict__ g, const int* __restrict__ h,
                 unsigned int* __restrict__ outT) {
    __shared__ float sw1[HID * 24];     // [j][k] row-major (96B rows, float4-aligned)
    __shared__ float sw2[HID * F_OUTD]; // transposed: [j][f]
    __shared__ float sb1[HID];
    __shared__ float sb2[F_OUTD];
    __shared__ int   sg[3], sh[3];

    int t = threadIdx.x;
    for (int idx = t; idx < HID * 24; idx += 256) sw1[idx] = w1[idx];
    for (int idx = t; idx < HID * F_OUTD; idx += 256) {
        int f = idx >> 6, j = idx & 63;
        sw2[j * F_OUTD + f] = w2[idx];
    }
    if (t < HID)    sb1[t] = b1[t];
    if (t < F_OUTD) sb2[t] = b2[t];

    int bx = blockIdx.x;
    int s_ = bx >> 12;        // / 4096
    int m  = bx & 4095;
    if (t < 3) {
        sg[t] = g[((size_t)s_ * 3 + t) * MDIM + m];
        sh[t] = h[((size_t)s_ * 3 + t) * MDIM + m];
    }
    __syncthreads();

    int r = t;
    // gather 24 features: c[i*8+f] = input[f, r, g_i]  (coalesced over r)
    float c[24];
#pragma unroll
    for (int i = 0; i < 3; i++) {
        int col = sg[i];
        const float* base = inT + (size_t)col * RDIM + r;
#pragma unroll
        for (int f = 0; f < F_IN; f++)
            c[i * 8 + f] = base[(size_t)f * CDIM * RDIM];
    }

    float of[F_OUTD];
#pragma unroll
    for (int f = 0; f < F_OUTD; f++) of[f] = sb2[f];

#pragma unroll 4
    for (int j = 0; j < HID; j++) {
        float a = sb1[j];
        const float4* wr = (const float4*)&sw1[j * 24];
#pragma unroll
        for (int q = 0; q < 6; q++) {
            float4 w = wr[q];
            a += w.x * c[q * 4 + 0] + w.y * c[q * 4 + 1]
               + w.z * c[q * 4 + 2] + w.w * c[q * 4 + 3];
        }
        a = fmaxf(a, 0.f);
        float4 wa = ((const float4*)&sw2[j * F_OUTD])[0];
        float4 wb = ((const float4*)&sw2[j * F_OUTD])[1];
        of[0] += a * wa.x; of[1] += a * wa.y; of[2] += a * wa.z; of[3] += a * wa.w;
        of[4] += a * wb.x; of[5] += a * wb.y; of[6] += a * wb.z; of[7] += a * wb.w;
    }

    // amax scatter to 3 destination columns; output >= 0 always (include_self over
    // zeros) so clamp at 0 and use uint-punned atomicMax (monotone for nonneg floats).
#pragma unroll
    for (int i = 0; i < 3; i++) {
        int col = sh[i];
        unsigned int* base = outT + (size_t)col * RDIM + r;
#pragma unroll
        for (int f = 0; f < F_OUTD; f++) {
            float v = of[f];
            if (v > 0.f)
                atomicMax(base + (size_t)f * CDIM * RDIM, __float_as_uint(v));
        }
    }
}

extern "C" void kernel_launch(void* const* d_in, const int* in_sizes, int n_in,
                              void* d_out, int out_size, void* d_ws, size_t ws_size,
                              hipStream_t stream) {
    const float* input = (const float*)d_in[0];
    const float* w1    = (const float*)d_in[1];
    const float* b1    = (const float*)d_in[2];
    const float* w2    = (const float*)d_in[3];
    const float* b2    = (const float*)d_in[4];
    const int*   ind0  = (const int*)d_in[5];
    const int*   ind1  = (const int*)d_in[6];
    const int*   ind2  = (const int*)d_in[7];
    const int*   mix   = (const int*)d_in[8];

    char* ws = (char*)d_ws;
    float*        inT  = (float*)ws;                            // 32 MiB
    unsigned int* outT = (unsigned int*)(ws + 33554432ull);     // 32 MiB
    int*          inv  = (int*)(ws + 67108864ull);              // 144 KiB
    int*          g    = (int*)(ws + 67256320ull);              // 144 KiB
    int*          h    = (int*)(ws + 67403776ull);              // 144 KiB

    int n4 = (F_OUTD * RDIM * CDIM) / 4;
    zero_kernel<<<(n4 + 255) / 256, 256, 0, stream>>>((float4*)outT, n4);

    dim3 tb(32, 8);
    transpose_f<<<dim3(CDIM / 32, RDIM / 32, F_IN), tb, 0, stream>>>(input, inT, RDIM, CDIM);

    build_inv<<<dim3(NIND / 256, 9), 256, 0, stream>>>(ind0, ind1, ind2, inv);
    build_gh<<<dim3(MDIM / 256, 9), 256, 0, stream>>>(ind0, ind1, ind2, mix, inv, g, h);

    mlp_scatter<<<NSETS * MDIM, 256, 0, stream>>>(inT, w1, b1, w2, b2, g, h, outT);

    transpose_f<<<dim3(RDIM / 32, CDIM / 32, F_OUTD), tb, 0, stream>>>(
        (const float*)outT, (float*)d_out, CDIM, RDIM);
}